// Round 2
// baseline (557.258 us; speedup 1.0000x reference)
//
#include <hip/hip_runtime.h>
#include <hip/hip_bf16.h>

#define DI __device__ __forceinline__

DI float bfu(unsigned short u){ return __uint_as_float(((unsigned)u)<<16); }
DI unsigned short f2b(float f){            // fp32 -> bf16 RNE
  unsigned u = __float_as_uint(f);
  return (unsigned short)((u + 0x7FFFu + ((u >> 16) & 1u)) >> 16);
}

typedef __attribute__((ext_vector_type(8))) short short8;   // 8 bf16 = 4 VGPRs
typedef __attribute__((ext_vector_type(4))) float floatx4;  // MFMA acc

// weight offsets inside fp32 workspace copy
#define OFF_W1  0
#define OFF_AS1 65536
#define OFF_AD1 65664
#define OFF_B1  65792
#define OFF_W2  65920
#define OFF_AS2 67968
#define OFF_AD2 67984
#define OFF_B2  68000
#define W_TOTAL 68016

#define CW_BLOCKS ((W_TOTAL+255)/256)      // 266
#define W1B_BLOCKS 256

// ---------------- fused setup: dtype sniff + weight converts + counts init ----------
__global__ __launch_bounds__(256) void setup_k(const unsigned short* __restrict__ x,
    const void* W1, const void* as1, const void* ad1, const void* b1,
    const void* W2, const void* as2, const void* ad2, const void* b2,
    int* __restrict__ flagp, float* __restrict__ dst,
    unsigned short* __restrict__ W1b, int* __restrict__ counts, int N){
  int b = blockIdx.x;
  if(b < CW_BLOCKS + W1B_BLOCKS){
    __shared__ int cnt;
    if(threadIdx.x==0) cnt = 0;
    __syncthreads();
    unsigned short u = x[threadIdx.x];
    int e = (u >> 7) & 0xFF;
    if(e < 100 || e > 140) atomicAdd(&cnt, 1);
    __syncthreads();
    int flag = (cnt >= 8) ? 1 : 0;           // 1 = fp32, 0 = bf16
    if(b == 0 && threadIdx.x == 0) *flagp = flag;
    if(b < CW_BLOCKS){
      int i = b*256 + threadIdx.x;
      if(i < W_TOTAL){
        const void* src; int off;
        if(i < OFF_AS1){ src=W1;  off=i; }
        else if(i < OFF_AD1){ src=as1; off=i-OFF_AS1; }
        else if(i < OFF_B1 ){ src=ad1; off=i-OFF_AD1; }
        else if(i < OFF_W2 ){ src=b1;  off=i-OFF_B1; }
        else if(i < OFF_AS2){ src=W2;  off=i-OFF_W2; }
        else if(i < OFF_AD2){ src=as2; off=i-OFF_AS2; }
        else if(i < OFF_B2 ){ src=ad2; off=i-OFF_AD2; }
        else               { src=b2;  off=i-OFF_B2; }
        dst[i] = flag ? ((const float*)src)[off]
                      : bfu(((const unsigned short*)src)[off]);
      }
    } else {
      int j = (b - CW_BLOCKS)*256 + threadIdx.x;   // < 65536
      W1b[j] = flag ? f2b(((const float*)W1)[j]) : ((const unsigned short*)W1)[j];
    }
  } else {
    int i = (b - CW_BLOCKS - W1B_BLOCKS)*256 + threadIdx.x;
    if(i < N) counts[i] = 1;                 // self-loop pre-counted
  }
}

// ---------------- CSR build ----------------
__global__ __launch_bounds__(256) void hist_k(const int* __restrict__ ei,
                                              int* __restrict__ counts, int E){
  int e = blockIdx.x*256 + threadIdx.x;
  if(e < E) atomicAdd(&counts[ei[E+e]], 1);
}

// -------- 3-phase parallel scan --------
__global__ __launch_bounds__(256) void bsum_k(const int* __restrict__ counts,
                                              int* __restrict__ bsum, int N){
  int i = blockIdx.x*256 + threadIdx.x;
  int v = (i < N) ? counts[i] : 0;
  #pragma unroll
  for(int o = 1; o < 64; o <<= 1) v += __shfl_xor(v, o);
  __shared__ int s[4];
  if((threadIdx.x & 63) == 0) s[threadIdx.x >> 6] = v;
  __syncthreads();
  if(threadIdx.x == 0) bsum[blockIdx.x] = s[0] + s[1] + s[2] + s[3];
}
__global__ __launch_bounds__(1024) void bscan_k(int* __restrict__ bsum, int nb){
  __shared__ int part[1024];
  int t = threadIdx.x;
  int v = (t < nb) ? bsum[t] : 0;
  part[t] = v;
  __syncthreads();
  for(int o = 1; o < 1024; o <<= 1){
    int u = (t >= o) ? part[t-o] : 0;
    __syncthreads();
    part[t] += u;
    __syncthreads();
  }
  if(t < nb) bsum[t] = part[t] - v;          // exclusive
}
__global__ __launch_bounds__(256) void csr_fill_k(const int* __restrict__ counts,
    const int* __restrict__ bsum, int* __restrict__ rowptr,
    int* __restrict__ cursor, int* __restrict__ csr_src, int N){
  __shared__ int part[256];
  int t = threadIdx.x;
  int i = blockIdx.x*256 + t;
  int c = (i < N) ? counts[i] : 0;
  part[t] = c;
  __syncthreads();
  for(int o = 1; o < 256; o <<= 1){
    int u = (t >= o) ? part[t-o] : 0;
    __syncthreads();
    part[t] += u;
    __syncthreads();
  }
  int excl = part[t] - c + bsum[blockIdx.x];
  if(i < N){
    rowptr[i] = excl;
    csr_src[excl] = i;                       // self-loop at slot 0 of row i
    cursor[i] = excl + 1;
    if(i == N-1) rowptr[N] = excl + c;
  }
}

// ---------------- XCD-range-partitioned scatter (see round-0 note) ----------------
__global__ __launch_bounds__(256) void scatter_k(const int* __restrict__ ei,
    int* __restrict__ cursor, int* __restrict__ csr_src, int E, int N){
  int r  = blockIdx.x & 7;                   // dst range == XCD (round-robin)
  int nb = gridDim.x >> 3;                   // blocks per range
  int bi = blockIdx.x >> 3;                  // block index within range
  int R  = (N + 7) >> 3;
  int lo = r * R;
  int hi = lo + R; if(hi > N) hi = N;
  for(int e = bi*256 + (int)threadIdx.x; e < E; e += nb*256){
    int d = ei[E + e];
    if(d >= lo && d < hi){
      int s = ei[e];
      int pos = atomicAdd(&cursor[d], 1);
      csr_src[pos] = s;
    }
  }
}

// ---------------- layer 1 MFMA GEMM: h1 = x @ W1^T (bf16) + attention logits --------
__global__ __launch_bounds__(256) void gemm1_mfma_k(const void* __restrict__ x,
    const int* __restrict__ flag, const unsigned short* __restrict__ W1b,
    const float* __restrict__ Wf, unsigned short* __restrict__ h1b,
    float* __restrict__ asrc1, float* __restrict__ adst1, int N){
  int wave = threadIdx.x >> 6, lane = threadIdx.x & 63;
  int q = lane >> 4, col = lane & 15;
  int nb = blockIdx.x*128 + wave*32;
  bool f32 = (*flag != 0);
  int cn0 = min(nb + col, N-1);
  int cn1 = min(nb + 16 + col, N-1);

  floatx4 acc[2][8];
  #pragma unroll
  for(int tm=0;tm<2;++tm)
    #pragma unroll
    for(int t=0;t<8;++t) acc[tm][t] = (floatx4){0.f,0.f,0.f,0.f};

  for(int ks=0; ks<16; ++ks){
    int k0 = ks*32 + q*8;
    short8 a0, a1;
    if(f32){
      const float* x0 = (const float*)x + (size_t)cn0*512 + k0;
      const float* x1 = (const float*)x + (size_t)cn1*512 + k0;
      union { short8 v; unsigned short u[8]; } A0, A1;
      #pragma unroll
      for(int j=0;j<8;++j){ A0.u[j] = f2b(x0[j]); A1.u[j] = f2b(x1[j]); }
      a0 = A0.v; a1 = A1.v;
    } else {
      a0 = *(const short8*)((const unsigned short*)x + (size_t)cn0*512 + k0);
      a1 = *(const short8*)((const unsigned short*)x + (size_t)cn1*512 + k0);
    }
    #pragma unroll
    for(int t=0;t<8;++t){
      short8 b = *(const short8*)(W1b + ((size_t)(16*t + col))*512 + k0);
      acc[0][t] = __builtin_amdgcn_mfma_f32_16x16x32_bf16(a0, b, acc[0][t], 0,0,0);
      acc[1][t] = __builtin_amdgcn_mfma_f32_16x16x32_bf16(a1, b, acc[1][t], 0,0,0);
    }
  }

  float asv[8], adv[8];
  #pragma unroll
  for(int t=0;t<8;++t){ asv[t] = Wf[OFF_AS1 + 16*t + col]; adv[t] = Wf[OFF_AD1 + 16*t + col]; }

  #pragma unroll
  for(int tm=0;tm<2;++tm){
    #pragma unroll
    for(int r=0;r<4;++r){
      int node = nb + tm*16 + q*4 + r;
      if(node >= N) continue;
      float vs = 0.f, vd = 0.f;
      #pragma unroll
      for(int t=0;t<8;++t){
        float v = acc[tm][t][r];
        h1b[(size_t)node*128 + 16*t + col] = f2b(v);
        float ps = v*asv[t], pd = v*adv[t];
        #pragma unroll
        for(int o=1;o<16;o<<=1){ ps += __shfl_xor(ps,o); pd += __shfl_xor(pd,o); }
        if(col == t){ vs = ps; vd = pd; }
      }
      if(col < 8){
        asrc1[(size_t)node*8 + col] = vs;
        adst1[(size_t)node*8 + col] = vd;
      }
    }
  }
}

// ---------------- layer 1 aggregate: 2-edge ping-pong pipeline ----------------
// Per group g (4 groups/wave): compute edge pair (A,B) while gathering pair (C,D)
// (issued a full pair earlier) and fetching CSR indices two pairs ahead. Halves
// loop-carried mov overhead and doubles gather issue-to-use distance vs depth-2.
__global__ __launch_bounds__(256) void agg1_k(const int* __restrict__ rowptr,
    const int* __restrict__ csr_src, const float* __restrict__ asrc1,
    const float* __restrict__ adst1, const unsigned short* __restrict__ h1b,
    const float* __restrict__ Wf,
    float* __restrict__ h2, float* __restrict__ asrc2, float* __restrict__ adst2, int N){
  int n = blockIdx.x*4 + (threadIdx.x >> 6);
  int lane = threadIdx.x & 63;
  if(n >= N) return;
  int g = lane >> 4;                 // edge group 0..3
  int cl = lane & 15;                // channel block: channels [8cl, 8cl+8)
  int h = cl >> 1;                   // head of this channel block
  float ad = adst1[n*8 + h];
  int end = rowptr[n+1];
  int p = rowptr[n] + g;

  float d = 0.f;
  float o[8];
  #pragma unroll
  for(int j=0;j<8;++j) o[j] = 0.f;

  union U { uint4 v; unsigned short u[8]; };
  const uint4 z4 = (uint4){0,0,0,0};

  // prologue: 4 slots of CSR, gathers for first pair
  bool vA = p    < end;
  bool vB = p+4  < end;
  bool vC = p+8  < end;
  bool vD = p+12 < end;
  int sA = vA ? csr_src[p]    : 0;
  int sB = vB ? csr_src[p+4]  : 0;
  int sC = vC ? csr_src[p+8]  : 0;
  int sD = vD ? csr_src[p+12] : 0;
  float aA = vA ? asrc1[sA*8 + h] : 0.f;
  float aB = vB ? asrc1[sB*8 + h] : 0.f;
  U HA, HB, HC, HD, HE, HF;
  HA.v = vA ? *(const uint4*)(h1b + (size_t)sA*128 + 8*cl) : z4;
  HB.v = vB ? *(const uint4*)(h1b + (size_t)sB*128 + 8*cl) : z4;
  int pn = p + 16;                    // next CSR fetch position

  while(vA){
    // -- half 1: fetch CSR (E,F); gather (C,D); compute (A,B) --
    bool vE = pn   < end;  int sE = vE ? csr_src[pn]   : 0;
    bool vF = pn+4 < end;  int sF = vF ? csr_src[pn+4] : 0;
    float aC = vC ? asrc1[sC*8 + h] : 0.f;
    float aD = vD ? asrc1[sD*8 + h] : 0.f;
    HC.v = vC ? *(const uint4*)(h1b + (size_t)sC*128 + 8*cl) : z4;
    HD.v = vD ? *(const uint4*)(h1b + (size_t)sD*128 + 8*cl) : z4;
    {
      float t0 = aA + ad; t0 = t0 > 0.f ? t0 : 0.2f*t0;
      float t1 = aB + ad; t1 = t1 > 0.f ? t1 : 0.2f*t1;
      float w0 = __expf(t0);
      float w1 = vB ? __expf(t1) : 0.f;
      d += w0 + w1;
      #pragma unroll
      for(int j=0;j<8;++j){
        o[j] = fmaf(w0, bfu(HA.u[j]), o[j]);
        o[j] = fmaf(w1, bfu(HB.u[j]), o[j]);
      }
    }
    if(!vC) break;
    // -- half 2: fetch CSR (new C,D); gather (E,F); compute (C,D) --
    bool vG = pn+8  < end;  int sG = vG ? csr_src[pn+8]  : 0;
    bool vH = pn+12 < end;  int sH = vH ? csr_src[pn+12] : 0;
    float aE = vE ? asrc1[sE*8 + h] : 0.f;
    float aF = vF ? asrc1[sF*8 + h] : 0.f;
    HE.v = vE ? *(const uint4*)(h1b + (size_t)sE*128 + 8*cl) : z4;
    HF.v = vF ? *(const uint4*)(h1b + (size_t)sF*128 + 8*cl) : z4;
    {
      float t0 = aC + ad; t0 = t0 > 0.f ? t0 : 0.2f*t0;
      float t1 = aD + ad; t1 = t1 > 0.f ? t1 : 0.2f*t1;
      float w0 = __expf(t0);
      float w1 = vD ? __expf(t1) : 0.f;
      d += w0 + w1;
      #pragma unroll
      for(int j=0;j<8;++j){
        o[j] = fmaf(w0, bfu(HC.u[j]), o[j]);
        o[j] = fmaf(w1, bfu(HD.u[j]), o[j]);
      }
    }
    // rotate: (A,B) <- (E,F); (C,D) <- (G,H)
    vA = vE; vB = vF; aA = aE; aB = aF; HA.v = HE.v; HB.v = HF.v;
    vC = vG; vD = vH; sC = sG; sD = sH;
    pn += 16;
  }

  // merge the 4 group partial sums
  #pragma unroll
  for(int off = 16; off < 64; off <<= 1){
    d += __shfl_xor(d, off);
    #pragma unroll
    for(int j=0;j<8;++j) o[j] += __shfl_xor(o[j], off);
  }

  float inv = 1.f / (d + 1e-16f);
  float e[8];
  #pragma unroll
  for(int j=0;j<8;++j){
    float v = o[j]*inv + Wf[OFF_B1 + 8*cl + j];
    e[j] = v > 0.f ? v : (__expf(v) - 1.f);  // ELU (fast exp; |err|~1e-7)
  }
  // distributed W2 epilogue: group g computes classes 4g..4g+3
  float h2v = 0.f;
  #pragma unroll
  for(int c = 0; c < 4; ++c){
    int cls = 4*g + c;
    const float4* wr = (const float4*)(Wf + OFF_W2 + cls*128 + 8*cl);
    float4 w0 = wr[0], w1 = wr[1];
    float part = w0.x*e[0] + w0.y*e[1] + w0.z*e[2] + w0.w*e[3]
               + w1.x*e[4] + w1.y*e[5] + w1.z*e[6] + w1.w*e[7];
    part += __shfl_xor(part,1); part += __shfl_xor(part,2);
    part += __shfl_xor(part,4); part += __shfl_xor(part,8);
    if(cl == c) h2v = part;                  // lane (g, cl<4) holds class 4g+cl
  }
  if(cl < 4) h2[n*16 + 4*g + cl] = h2v;
  float ps = (cl < 4) ? h2v * Wf[OFF_AS2 + 4*g + cl] : 0.f;
  float pd = (cl < 4) ? h2v * Wf[OFF_AD2 + 4*g + cl] : 0.f;
  #pragma unroll
  for(int off = 1; off < 64; off <<= 1){ ps += __shfl_xor(ps,off); pd += __shfl_xor(pd,off); }
  if(lane == 0){ asrc2[n] = ps; adst2[n] = pd; }
}

// ---------------- layer 2 aggregate: 2-edge ping-pong pipeline, log_softmax ------
__global__ __launch_bounds__(256) void agg2_k(const int* __restrict__ rowptr,
    const int* __restrict__ csr_src, const float* __restrict__ asrc2,
    const float* __restrict__ adst2, const float* __restrict__ h2,
    const float* __restrict__ Wf, const int* __restrict__ flag,
    void* __restrict__ out, int N){
  int n = blockIdx.x*4 + (threadIdx.x >> 6);
  int lane = threadIdx.x & 63;
  if(n >= N) return;
  int g = lane >> 4, l = lane & 15;
  float ad = adst2[n];
  int end = rowptr[n+1];
  int p = rowptr[n] + g;

  float d = 0.f, o = 0.f;

  bool vA = p    < end;
  bool vB = p+4  < end;
  bool vC = p+8  < end;
  bool vD = p+12 < end;
  int sA = vA ? csr_src[p]    : 0;
  int sB = vB ? csr_src[p+4]  : 0;
  int sC = vC ? csr_src[p+8]  : 0;
  int sD = vD ? csr_src[p+12] : 0;
  float aA = vA ? asrc2[sA] : 0.f;
  float aB = vB ? asrc2[sB] : 0.f;
  float hA = vA ? h2[sA*16 + l] : 0.f;
  float hB = vB ? h2[sB*16 + l] : 0.f;
  int pn = p + 16;

  while(vA){
    // -- half 1 --
    bool vE = pn   < end;  int sE = vE ? csr_src[pn]   : 0;
    bool vF = pn+4 < end;  int sF = vF ? csr_src[pn+4] : 0;
    float aC = vC ? asrc2[sC] : 0.f;
    float aD = vD ? asrc2[sD] : 0.f;
    float hC = vC ? h2[sC*16 + l] : 0.f;
    float hD = vD ? h2[sD*16 + l] : 0.f;
    {
      float t0 = aA + ad; t0 = t0 > 0.f ? t0 : 0.2f*t0;
      float t1 = aB + ad; t1 = t1 > 0.f ? t1 : 0.2f*t1;
      float w0 = __expf(t0);
      float w1 = vB ? __expf(t1) : 0.f;
      d += w0 + w1;
      o = fmaf(w0, hA, o);
      o = fmaf(w1, hB, o);
    }
    if(!vC) break;
    // -- half 2 --
    bool vG = pn+8  < end;  int sG = vG ? csr_src[pn+8]  : 0;
    bool vH = pn+12 < end;  int sH = vH ? csr_src[pn+12] : 0;
    float aE = vE ? asrc2[sE] : 0.f;
    float aF = vF ? asrc2[sF] : 0.f;
    float hE = vE ? h2[sE*16 + l] : 0.f;
    float hF = vF ? h2[sF*16 + l] : 0.f;
    {
      float t0 = aC + ad; t0 = t0 > 0.f ? t0 : 0.2f*t0;
      float t1 = aD + ad; t1 = t1 > 0.f ? t1 : 0.2f*t1;
      float w0 = __expf(t0);
      float w1 = vD ? __expf(t1) : 0.f;
      d += w0 + w1;
      o = fmaf(w0, hC, o);
      o = fmaf(w1, hD, o);
    }
    vA = vE; vB = vF; aA = aE; aB = aF; hA = hE; hB = hF;
    vC = vG; vD = vH; sC = sG; sD = sH;
    pn += 16;
  }

  #pragma unroll
  for(int off = 16; off < 64; off <<= 1){
    d += __shfl_xor(d, off);
    o += __shfl_xor(o, off);
  }

  float v = o/(d + 1e-16f) + Wf[OFF_B2 + l];
  float mx = v;
  #pragma unroll
  for(int off = 1; off < 16; off <<= 1) mx = fmaxf(mx, __shfl_xor(mx, off));
  float ex = __expf(v - mx), sum = ex;
  #pragma unroll
  for(int off = 1; off < 16; off <<= 1) sum += __shfl_xor(sum, off);
  float r = v - mx - __logf(sum);
  if(g == 0){
    if(*flag) ((float*)out)[(size_t)n*16 + l] = r;
    else      ((__hip_bfloat16*)out)[(size_t)n*16 + l] = __float2bfloat16(r);
  }
}

extern "C" void kernel_launch(void* const* d_in, const int* in_sizes, int n_in,
                              void* d_out, int out_size, void* d_ws, size_t ws_size,
                              hipStream_t stream){
  const void* x  = d_in[0];
  const int*  ei = (const int*)d_in[1];
  const int N  = in_sizes[0] / 512;
  const int E  = in_sizes[1] / 2;
  const int NB = (N + 255) / 256;            // scan blocks (196 for N=50000)

  // workspace layout
  int*   flag     = (int*)d_ws;
  float* Wf       = (float*)d_ws + 4;                    // W_TOTAL
  unsigned short* W1b = (unsigned short*)(Wf + W_TOTAL); // 65536 ushort
  unsigned short* h1b = W1b + 65536;                     // N*128 ushort
  float* asrc1    = (float*)(h1b + (size_t)N*128);       // N*8
  float* adst1    = asrc1 + (size_t)N*8;                 // N*8
  float* h2       = adst1 + (size_t)N*8;                 // N*16
  float* asrc2    = h2 + (size_t)N*16;                   // N
  float* adst2    = asrc2 + N;                           // N
  int*   rowptr   = (int*)(adst2 + N);                   // N+1
  int*   cursor   = rowptr + (N+1);                      // N (counts)
  int*   csr_src  = cursor + N;                          // E+N
  int*   bsum     = csr_src + (E+N);                     // NB

  int setup_blocks = CW_BLOCKS + W1B_BLOCKS + NB;
  hipLaunchKernelGGL(setup_k, dim3(setup_blocks), dim3(256), 0, stream,
                     (const unsigned short*)x,
                     d_in[2], d_in[3], d_in[4], d_in[5], d_in[6], d_in[7], d_in[8], d_in[9],
                     flag, Wf, W1b, cursor, N);
  hipLaunchKernelGGL(hist_k, dim3((E+255)/256), dim3(256), 0, stream, ei, cursor, E);
  hipLaunchKernelGGL(bsum_k, dim3(NB), dim3(256), 0, stream, cursor, bsum, N);
  hipLaunchKernelGGL(bscan_k, dim3(1), dim3(1024), 0, stream, bsum, NB);
  hipLaunchKernelGGL(csr_fill_k, dim3(NB), dim3(256), 0, stream,
                     cursor, bsum, rowptr, cursor, csr_src, N);
  hipLaunchKernelGGL(scatter_k, dim3(1024), dim3(256), 0, stream,
                     ei, cursor, csr_src, E, N);
  hipLaunchKernelGGL(gemm1_mfma_k, dim3((N+127)/128), dim3(256), 0, stream,
                     x, flag, W1b, Wf, h1b, asrc1, adst1, N);
  hipLaunchKernelGGL(agg1_k, dim3((N+3)/4), dim3(256), 0, stream,
                     rowptr, csr_src, asrc1, adst1, h1b, Wf, h2, asrc2, adst2, N);
  hipLaunchKernelGGL(agg2_k, dim3((N+3)/4), dim3(256), 0, stream,
                     rowptr, csr_src, asrc2, adst2, h2, Wf, flag, d_out, N);
}

// Round 3
// 481.464 us; speedup vs baseline: 1.1574x; 1.1574x over previous
//
#include <hip/hip_runtime.h>
#include <hip/hip_bf16.h>

#define DI __device__ __forceinline__

DI float bfu(unsigned short u){ return __uint_as_float(((unsigned)u)<<16); }
DI unsigned short f2b(float f){            // fp32 -> bf16 RNE
  unsigned u = __float_as_uint(f);
  return (unsigned short)((u + 0x7FFFu + ((u >> 16) & 1u)) >> 16);
}

typedef __attribute__((ext_vector_type(8))) short short8;   // 8 bf16 = 4 VGPRs
typedef __attribute__((ext_vector_type(4))) float floatx4;  // MFMA acc

// weight offsets inside fp32 workspace copy
#define OFF_W1  0
#define OFF_AS1 65536
#define OFF_AD1 65664
#define OFF_B1  65792
#define OFF_W2  65920
#define OFF_AS2 67968
#define OFF_AD2 67984
#define OFF_B2  68000
#define W_TOTAL 68016

#define CW_BLOCKS ((W_TOTAL+255)/256)      // 266
#define W1B_BLOCKS 256

// ---------------- fused setup: dtype sniff + weight converts + counts init ----------
__global__ __launch_bounds__(256) void setup_k(const unsigned short* __restrict__ x,
    const void* W1, const void* as1, const void* ad1, const void* b1,
    const void* W2, const void* as2, const void* ad2, const void* b2,
    int* __restrict__ flagp, float* __restrict__ dst,
    unsigned short* __restrict__ W1b, int* __restrict__ counts, int N){
  int b = blockIdx.x;
  if(b < CW_BLOCKS + W1B_BLOCKS){
    __shared__ int cnt;
    if(threadIdx.x==0) cnt = 0;
    __syncthreads();
    unsigned short u = x[threadIdx.x];
    int e = (u >> 7) & 0xFF;
    if(e < 100 || e > 140) atomicAdd(&cnt, 1);
    __syncthreads();
    int flag = (cnt >= 8) ? 1 : 0;           // 1 = fp32, 0 = bf16
    if(b == 0 && threadIdx.x == 0) *flagp = flag;
    if(b < CW_BLOCKS){
      int i = b*256 + threadIdx.x;
      if(i < W_TOTAL){
        const void* src; int off;
        if(i < OFF_AS1){ src=W1;  off=i; }
        else if(i < OFF_AD1){ src=as1; off=i-OFF_AS1; }
        else if(i < OFF_B1 ){ src=ad1; off=i-OFF_AD1; }
        else if(i < OFF_W2 ){ src=b1;  off=i-OFF_B1; }
        else if(i < OFF_AS2){ src=W2;  off=i-OFF_W2; }
        else if(i < OFF_AD2){ src=as2; off=i-OFF_AS2; }
        else if(i < OFF_B2 ){ src=ad2; off=i-OFF_AD2; }
        else               { src=b2;  off=i-OFF_B2; }
        dst[i] = flag ? ((const float*)src)[off]
                      : bfu(((const unsigned short*)src)[off]);
      }
    } else {
      int j = (b - CW_BLOCKS)*256 + threadIdx.x;   // < 65536
      W1b[j] = flag ? f2b(((const float*)W1)[j]) : ((const unsigned short*)W1)[j];
    }
  } else {
    int i = (b - CW_BLOCKS - W1B_BLOCKS)*256 + threadIdx.x;
    if(i < N) counts[i] = 1;                 // self-loop pre-counted
  }
}

// ---------------- CSR build ----------------
__global__ __launch_bounds__(256) void hist_k(const int* __restrict__ ei,
                                              int* __restrict__ counts, int E){
  int e = blockIdx.x*256 + threadIdx.x;
  if(e < E) atomicAdd(&counts[ei[E+e]], 1);
}

// -------- 3-phase parallel scan --------
__global__ __launch_bounds__(256) void bsum_k(const int* __restrict__ counts,
                                              int* __restrict__ bsum, int N){
  int i = blockIdx.x*256 + threadIdx.x;
  int v = (i < N) ? counts[i] : 0;
  #pragma unroll
  for(int o = 1; o < 64; o <<= 1) v += __shfl_xor(v, o);
  __shared__ int s[4];
  if((threadIdx.x & 63) == 0) s[threadIdx.x >> 6] = v;
  __syncthreads();
  if(threadIdx.x == 0) bsum[blockIdx.x] = s[0] + s[1] + s[2] + s[3];
}
__global__ __launch_bounds__(1024) void bscan_k(int* __restrict__ bsum, int nb){
  __shared__ int part[1024];
  int t = threadIdx.x;
  int v = (t < nb) ? bsum[t] : 0;
  part[t] = v;
  __syncthreads();
  for(int o = 1; o < 1024; o <<= 1){
    int u = (t >= o) ? part[t-o] : 0;
    __syncthreads();
    part[t] += u;
    __syncthreads();
  }
  if(t < nb) bsum[t] = part[t] - v;          // exclusive
}
__global__ __launch_bounds__(256) void csr_fill_k(const int* __restrict__ counts,
    const int* __restrict__ bsum, int* __restrict__ rowptr,
    int* __restrict__ cursor, int* __restrict__ csr_src, int N){
  __shared__ int part[256];
  int t = threadIdx.x;
  int i = blockIdx.x*256 + t;
  int c = (i < N) ? counts[i] : 0;
  part[t] = c;
  __syncthreads();
  for(int o = 1; o < 256; o <<= 1){
    int u = (t >= o) ? part[t-o] : 0;
    __syncthreads();
    part[t] += u;
    __syncthreads();
  }
  int excl = part[t] - c + bsum[blockIdx.x];
  if(i < N){
    rowptr[i] = excl;
    csr_src[excl] = i;                       // self-loop at slot 0 of row i
    cursor[i] = excl + 1;
    if(i == N-1) rowptr[N] = excl + c;
  }
}

// ---------------- XCD-range-partitioned scatter (see round-0 note) ----------------
__global__ __launch_bounds__(256) void scatter_k(const int* __restrict__ ei,
    int* __restrict__ cursor, int* __restrict__ csr_src, int E, int N){
  int r  = blockIdx.x & 7;                   // dst range == XCD (round-robin)
  int nb = gridDim.x >> 3;                   // blocks per range
  int bi = blockIdx.x >> 3;                  // block index within range
  int R  = (N + 7) >> 3;
  int lo = r * R;
  int hi = lo + R; if(hi > N) hi = N;
  for(int e = bi*256 + (int)threadIdx.x; e < E; e += nb*256){
    int d = ei[E + e];
    if(d >= lo && d < hi){
      int s = ei[e];
      int pos = atomicAdd(&cursor[d], 1);
      csr_src[pos] = s;
    }
  }
}

// ---------------- layer 1 MFMA GEMM: h1 = x @ W1^T (bf16) + attention logits --------
__global__ __launch_bounds__(256) void gemm1_mfma_k(const void* __restrict__ x,
    const int* __restrict__ flag, const unsigned short* __restrict__ W1b,
    const float* __restrict__ Wf, unsigned short* __restrict__ h1b,
    float* __restrict__ asrc1, float* __restrict__ adst1, int N){
  int wave = threadIdx.x >> 6, lane = threadIdx.x & 63;
  int q = lane >> 4, col = lane & 15;
  int nb = blockIdx.x*128 + wave*32;
  bool f32 = (*flag != 0);
  int cn0 = min(nb + col, N-1);
  int cn1 = min(nb + 16 + col, N-1);

  floatx4 acc[2][8];
  #pragma unroll
  for(int tm=0;tm<2;++tm)
    #pragma unroll
    for(int t=0;t<8;++t) acc[tm][t] = (floatx4){0.f,0.f,0.f,0.f};

  for(int ks=0; ks<16; ++ks){
    int k0 = ks*32 + q*8;
    short8 a0, a1;
    if(f32){
      const float* x0 = (const float*)x + (size_t)cn0*512 + k0;
      const float* x1 = (const float*)x + (size_t)cn1*512 + k0;
      union { short8 v; unsigned short u[8]; } A0, A1;
      #pragma unroll
      for(int j=0;j<8;++j){ A0.u[j] = f2b(x0[j]); A1.u[j] = f2b(x1[j]); }
      a0 = A0.v; a1 = A1.v;
    } else {
      a0 = *(const short8*)((const unsigned short*)x + (size_t)cn0*512 + k0);
      a1 = *(const short8*)((const unsigned short*)x + (size_t)cn1*512 + k0);
    }
    #pragma unroll
    for(int t=0;t<8;++t){
      short8 b = *(const short8*)(W1b + ((size_t)(16*t + col))*512 + k0);
      acc[0][t] = __builtin_amdgcn_mfma_f32_16x16x32_bf16(a0, b, acc[0][t], 0,0,0);
      acc[1][t] = __builtin_amdgcn_mfma_f32_16x16x32_bf16(a1, b, acc[1][t], 0,0,0);
    }
  }

  float asv[8], adv[8];
  #pragma unroll
  for(int t=0;t<8;++t){ asv[t] = Wf[OFF_AS1 + 16*t + col]; adv[t] = Wf[OFF_AD1 + 16*t + col]; }

  #pragma unroll
  for(int tm=0;tm<2;++tm){
    #pragma unroll
    for(int r=0;r<4;++r){
      int node = nb + tm*16 + q*4 + r;
      if(node >= N) continue;
      float vs = 0.f, vd = 0.f;
      #pragma unroll
      for(int t=0;t<8;++t){
        float v = acc[tm][t][r];
        h1b[(size_t)node*128 + 16*t + col] = f2b(v);
        float ps = v*asv[t], pd = v*adv[t];
        #pragma unroll
        for(int o=1;o<16;o<<=1){ ps += __shfl_xor(ps,o); pd += __shfl_xor(pd,o); }
        if(col == t){ vs = ps; vd = pd; }
      }
      if(col < 8){
        asrc1[(size_t)node*8 + col] = vs;
        adst1[(size_t)node*8 + col] = vd;
      }
    }
  }
}

// ---------------- layer 1 aggregate: round-1 structure, gathers now 2 iters ahead ----
// Single edge per iter, branch-free guarded loads (if-converted), single loop exit.
// CSR index fetched 3 ahead; asrc/h1b gathers issued 2 ahead (was 1) to cover the
// ~200-500cy L2/L3 gather latency. +7 VGPR, no occupancy loss.
__global__ __launch_bounds__(256) void agg1_k(const int* __restrict__ rowptr,
    const int* __restrict__ csr_src, const float* __restrict__ asrc1,
    const float* __restrict__ adst1, const unsigned short* __restrict__ h1b,
    const float* __restrict__ Wf,
    float* __restrict__ h2, float* __restrict__ asrc2, float* __restrict__ adst2, int N){
  int n = blockIdx.x*4 + (threadIdx.x >> 6);
  int lane = threadIdx.x & 63;
  if(n >= N) return;
  int g = lane >> 4;                 // edge group 0..3
  int cl = lane & 15;                // channel block: channels [8cl, 8cl+8)
  int h = cl >> 1;                   // head of this channel block
  float ad = adst1[n*8 + h];
  int end = rowptr[n+1];
  int p = rowptr[n] + g;

  float d = 0.f;
  float o[8];
  #pragma unroll
  for(int j=0;j<8;++j) o[j] = 0.f;

  union U { uint4 v; unsigned short u[8]; };
  const uint4 z4 = (uint4){0,0,0,0};

  bool v0 = p    < end;
  bool v1 = p+4  < end;
  bool v2 = p+8  < end;
  bool v3 = p+12 < end;
  int s0 = v0 ? csr_src[p]    : 0;
  int s1 = v1 ? csr_src[p+4]  : 0;
  int s2 = v2 ? csr_src[p+8]  : 0;
  float a0 = v0 ? asrc1[s0*8 + h] : 0.f;
  float a1 = v1 ? asrc1[s1*8 + h] : 0.f;
  U H0, H1, H2;
  H0.v = v0 ? *(const uint4*)(h1b + (size_t)s0*128 + 8*cl) : z4;
  H1.v = v1 ? *(const uint4*)(h1b + (size_t)s1*128 + 8*cl) : z4;

  while(v0){
    int s3 = v3 ? csr_src[p+12] : 0;            // csr, 3 ahead
    float a2 = v2 ? asrc1[s2*8 + h] : 0.f;      // gathers, 2 ahead
    H2.v = v2 ? *(const uint4*)(h1b + (size_t)s2*128 + 8*cl) : z4;
    float aa = a0 + ad;
    aa = aa > 0.f ? aa : 0.2f*aa;               // leaky_relu
    float w = __expf(aa);
    d += w;
    #pragma unroll
    for(int j=0;j<8;++j) o[j] = fmaf(w, bfu(H0.u[j]), o[j]);
    p += 4;
    v0 = v1; v1 = v2; v2 = v3; v3 = (p+12 < end);
    s2 = s3;
    a0 = a1; a1 = a2;
    H0.v = H1.v; H1.v = H2.v;
  }

  // merge the 4 group partial sums (plain adds)
  #pragma unroll
  for(int off = 16; off < 64; off <<= 1){
    d += __shfl_xor(d, off);
    #pragma unroll
    for(int j=0;j<8;++j) o[j] += __shfl_xor(o[j], off);
  }

  float inv = 1.f / (d + 1e-16f);
  float e[8];
  #pragma unroll
  for(int j=0;j<8;++j){
    float v = o[j]*inv + Wf[OFF_B1 + 8*cl + j];
    e[j] = v > 0.f ? v : (__expf(v) - 1.f);    // ELU (fast exp; |err|~1e-7)
  }
  // distributed W2 epilogue: group g computes classes 4g..4g+3
  float h2v = 0.f;
  #pragma unroll
  for(int c = 0; c < 4; ++c){
    int cls = 4*g + c;
    const float4* wr = (const float4*)(Wf + OFF_W2 + cls*128 + 8*cl);
    float4 w0 = wr[0], w1 = wr[1];
    float part = w0.x*e[0] + w0.y*e[1] + w0.z*e[2] + w0.w*e[3]
               + w1.x*e[4] + w1.y*e[5] + w1.z*e[6] + w1.w*e[7];
    part += __shfl_xor(part,1); part += __shfl_xor(part,2);
    part += __shfl_xor(part,4); part += __shfl_xor(part,8);
    if(cl == c) h2v = part;                  // lane (g, cl<4) holds class 4g+cl
  }
  if(cl < 4) h2[n*16 + 4*g + cl] = h2v;
  float ps = (cl < 4) ? h2v * Wf[OFF_AS2 + 4*g + cl] : 0.f;
  float pd = (cl < 4) ? h2v * Wf[OFF_AD2 + 4*g + cl] : 0.f;
  #pragma unroll
  for(int off = 1; off < 64; off <<= 1){ ps += __shfl_xor(ps,off); pd += __shfl_xor(pd,off); }
  if(lane == 0){ asrc2[n] = ps; adst2[n] = pd; }
}

// ---------------- layer 2 aggregate: round-1 structure, gathers 2 iters ahead -------
__global__ __launch_bounds__(256) void agg2_k(const int* __restrict__ rowptr,
    const int* __restrict__ csr_src, const float* __restrict__ asrc2,
    const float* __restrict__ adst2, const float* __restrict__ h2,
    const float* __restrict__ Wf, const int* __restrict__ flag,
    void* __restrict__ out, int N){
  int n = blockIdx.x*4 + (threadIdx.x >> 6);
  int lane = threadIdx.x & 63;
  if(n >= N) return;
  int g = lane >> 4, l = lane & 15;
  float ad = adst2[n];
  int end = rowptr[n+1];
  int p = rowptr[n] + g;

  float d = 0.f, o = 0.f;

  bool v0 = p    < end;
  bool v1 = p+4  < end;
  bool v2 = p+8  < end;
  bool v3 = p+12 < end;
  int s0 = v0 ? csr_src[p]    : 0;
  int s1 = v1 ? csr_src[p+4]  : 0;
  int s2 = v2 ? csr_src[p+8]  : 0;
  float a0 = v0 ? asrc2[s0] : 0.f;
  float a1 = v1 ? asrc2[s1] : 0.f;
  float h0 = v0 ? h2[s0*16 + l] : 0.f;
  float h1v = v1 ? h2[s1*16 + l] : 0.f;

  while(v0){
    int s3 = v3 ? csr_src[p+12] : 0;            // csr, 3 ahead
    float a2 = v2 ? asrc2[s2] : 0.f;            // gathers, 2 ahead
    float h2g = v2 ? h2[s2*16 + l] : 0.f;
    float aa = a0 + ad;
    aa = aa > 0.f ? aa : 0.2f*aa;
    float w = __expf(aa);
    d += w;
    o = fmaf(w, h0, o);
    p += 4;
    v0 = v1; v1 = v2; v2 = v3; v3 = (p+12 < end);
    s2 = s3;
    a0 = a1; a1 = a2;
    h0 = h1v; h1v = h2g;
  }

  #pragma unroll
  for(int off = 16; off < 64; off <<= 1){
    d += __shfl_xor(d, off);
    o += __shfl_xor(o, off);
  }

  float v = o/(d + 1e-16f) + Wf[OFF_B2 + l];
  float mx = v;
  #pragma unroll
  for(int off = 1; off < 16; off <<= 1) mx = fmaxf(mx, __shfl_xor(mx, off));
  float ex = __expf(v - mx), sum = ex;
  #pragma unroll
  for(int off = 1; off < 16; off <<= 1) sum += __shfl_xor(sum, off);
  float r = v - mx - __logf(sum);
  if(g == 0){
    if(*flag) ((float*)out)[(size_t)n*16 + l] = r;
    else      ((__hip_bfloat16*)out)[(size_t)n*16 + l] = __float2bfloat16(r);
  }
}

extern "C" void kernel_launch(void* const* d_in, const int* in_sizes, int n_in,
                              void* d_out, int out_size, void* d_ws, size_t ws_size,
                              hipStream_t stream){
  const void* x  = d_in[0];
  const int*  ei = (const int*)d_in[1];
  const int N  = in_sizes[0] / 512;
  const int E  = in_sizes[1] / 2;
  const int NB = (N + 255) / 256;            // scan blocks (196 for N=50000)

  // workspace layout
  int*   flag     = (int*)d_ws;
  float* Wf       = (float*)d_ws + 4;                    // W_TOTAL
  unsigned short* W1b = (unsigned short*)(Wf + W_TOTAL); // 65536 ushort
  unsigned short* h1b = W1b + 65536;                     // N*128 ushort
  float* asrc1    = (float*)(h1b + (size_t)N*128);       // N*8
  float* adst1    = asrc1 + (size_t)N*8;                 // N*8
  float* h2       = adst1 + (size_t)N*8;                 // N*16
  float* asrc2    = h2 + (size_t)N*16;                   // N
  float* adst2    = asrc2 + N;                           // N
  int*   rowptr   = (int*)(adst2 + N);                   // N+1
  int*   cursor   = rowptr + (N+1);                      // N (counts)
  int*   csr_src  = cursor + N;                          // E+N
  int*   bsum     = csr_src + (E+N);                     // NB

  int setup_blocks = CW_BLOCKS + W1B_BLOCKS + NB;
  hipLaunchKernelGGL(setup_k, dim3(setup_blocks), dim3(256), 0, stream,
                     (const unsigned short*)x,
                     d_in[2], d_in[3], d_in[4], d_in[5], d_in[6], d_in[7], d_in[8], d_in[9],
                     flag, Wf, W1b, cursor, N);
  hipLaunchKernelGGL(hist_k, dim3((E+255)/256), dim3(256), 0, stream, ei, cursor, E);
  hipLaunchKernelGGL(bsum_k, dim3(NB), dim3(256), 0, stream, cursor, bsum, N);
  hipLaunchKernelGGL(bscan_k, dim3(1), dim3(1024), 0, stream, bsum, NB);
  hipLaunchKernelGGL(csr_fill_k, dim3(NB), dim3(256), 0, stream,
                     cursor, bsum, rowptr, cursor, csr_src, N);
  hipLaunchKernelGGL(scatter_k, dim3(1024), dim3(256), 0, stream,
                     ei, cursor, csr_src, E, N);
  hipLaunchKernelGGL(gemm1_mfma_k, dim3((N+127)/128), dim3(256), 0, stream,
                     x, flag, W1b, Wf, h1b, asrc1, adst1, N);
  hipLaunchKernelGGL(agg1_k, dim3((N+3)/4), dim3(256), 0, stream,
                     rowptr, csr_src, asrc1, adst1, h1b, Wf, h2, asrc2, adst2, N);
  hipLaunchKernelGGL(agg2_k, dim3((N+3)/4), dim3(256), 0, stream,
                     rowptr, csr_src, asrc2, adst2, h2, Wf, flag, d_out, N);
}